// Round 4
// baseline (236.553 us; speedup 1.0000x reference)
//
#include <hip/hip_runtime.h>
#include <math.h>

// PerBandSoftAGC: out = x / (clip(EMA_FIR(|x|), eps)^alpha + delta)
// EMA FIR (L=100 taps j=0..99, geometric) via exact sliding recursion:
//   M[t] = q*M[t-1] + w0*|x[t]| - w0*q^100 * |x[t-100]|
// R6: no LDS staging; tail-drop chunk = second coalesced global load (L1/L2
//     hot); full-fp32 path; chunk-prefix Horner init; nt store.
// R7: CHUNK 8 (BLOCK=256). R6 post-mortem: residual ~67us is per-thread init
//     cost (25 LDS reads + 24-FMA Horner + barrier per 4 outputs) -> 512
//     waves/CU * ~15 DS instr * ~6cyc ~= 19us LDS pipe + duplicated scalar
//     work. 100 = 12*8 + 4: window = Horner over 12 8-chunk prefixes + a
//     4-element correction that is free (tail-drop load pv0 holds elements
//     8t-100..8t-97). Threads halve; DS amortization 2.4x; IO = two float4
//     per thread at 32B lane stride = one 64B sector per line per instr
//     (sector-optimal, unlike R3's 128B-stride scatter).

constexpr int T      = 8192;
constexpr int KC_    = 128;
constexpr int LEN    = 100;
constexpr int BLOCK  = 256;
constexpr int CHUNK  = 8;
constexpr int SEG    = BLOCK * CHUNK;   // 2048 elements per block
constexpr int NSEG   = T / SEG;         // 4 blocks per row
constexpr int NH8    = 12;              // full 8-chunks in the 100-elem window
constexpr float EPS_   = 1e-6f;
constexpr float DELTA_ = 0.1f;
constexpr float LOG2E  = 1.4426950408889634f;

typedef float f32x4 __attribute__((ext_vector_type(4)));

__device__ __forceinline__ float fast_sigmoid(float x) {
    const float e = __builtin_amdgcn_exp2f(-x * LOG2E);
    return __builtin_amdgcn_rcpf(1.0f + e);
}

__device__ __forceinline__ float gain_div(float xv, float M, float alpha) {
    const float Mc = fmaxf(M, EPS_);
    // Mc^alpha = exp2(alpha * log2(Mc)); v_log_f32 is log2, v_exp_f32 is exp2
    const float g  = __builtin_amdgcn_exp2f(alpha * __builtin_amdgcn_logf(Mc)) + DELTA_;
    return xv * __builtin_amdgcn_rcpf(g);   // g >= delta = 0.1, rcp safe
}

// 8-element chunk prefix: sum_{i=0..7} q^{7-i} |e_i|
__device__ __forceinline__ float prefix8(float q, const f32x4& u, const f32x4& w) {
    float p = fabsf(u.x);
    p = fmaf(q, p, fabsf(u.y));
    p = fmaf(q, p, fabsf(u.z));
    p = fmaf(q, p, fabsf(u.w));
    p = fmaf(q, p, fabsf(w.x));
    p = fmaf(q, p, fabsf(w.y));
    p = fmaf(q, p, fabsf(w.z));
    p = fmaf(q, p, fabsf(w.w));
    return p;
}

__global__ __launch_bounds__(BLOCK, 8) void agc_kernel(
    const float* __restrict__ x,
    const float* __restrict__ alpha_raw,
    const float* __restrict__ log_s,
    float* __restrict__ out)
{
    __shared__ float Pe[NH8 + BLOCK];      // 268 floats = 1072 B

    const int bid = blockIdx.x;
    const int row = bid >> 2;              // NSEG = 4
    const int seg = bid & (NSEG - 1);      // consecutive blocks share a row
    const int g4  = (seg * SEG) >> 2;      // segment start, float4 units
    const int kc  = row & (KC_ - 1);
    const int tid = threadIdx.x;
    const float* __restrict__ xrow = x + (size_t)row * T;
    float* __restrict__ orow       = out + (size_t)row * T;
    const f32x4* __restrict__ x4   = reinterpret_cast<const f32x4*>(xrow);
    f32x4* __restrict__ o4         = reinterpret_cast<f32x4*>(orow);

    // ---- per-channel scalars (block-uniform) ----
    const float s     = fast_sigmoid(log_s[kc]);
    const float alpha = 0.5f * fast_sigmoid(alpha_raw[kc]);
    const float q     = 1.0f - s;
    const float lq    = __builtin_amdgcn_logf(q);          // log2(q)
    const float q4    = (q * q) * (q * q);
    const float q8    = q4 * q4;
    const float q100  = __builtin_amdgcn_exp2f(100.0f * lq);
    const float norm  = (1.0f - q100) + 1e-8f;   // sum of unnormalized weights
    const float w0    = s / norm;                // normalized weight j=0
    const float c3    = w0 * q100;               // tail-drop coefficient

    const int i40 = g4 + 2 * tid;          // own first float4 index

    // ---- own chunk (2 float4) + tail-drop chunk (2 float4, offset -25) ----
    const f32x4 v0 = x4[i40];
    const f32x4 v1 = x4[i40 + 1];
    f32x4 p0 = {0.0f, 0.0f, 0.0f, 0.0f};
    f32x4 p1 = {0.0f, 0.0f, 0.0f, 0.0f};
    if (seg != 0 || tid >= 13) p0 = x4[i40 - 25];   // elements 8t-100..8t-97
    if (seg != 0 || tid >= 12) p1 = x4[i40 - 24];   // elements 8t-96..8t-93

    // ---- halo 8-chunk prefixes: chunks -12..-1 (zeros at row start) ----
    if (tid < NH8) {
        f32x4 h0 = {0.0f, 0.0f, 0.0f, 0.0f};
        f32x4 h1 = {0.0f, 0.0f, 0.0f, 0.0f};
        if (seg != 0) {
            h0 = x4[g4 + 2 * (tid - NH8)];
            h1 = x4[g4 + 2 * (tid - NH8) + 1];
        }
        Pe[tid] = prefix8(q, h0, h1);
    }

    const float a0 = fabsf(v0.x), a1 = fabsf(v0.y), a2 = fabsf(v0.z), a3 = fabsf(v0.w);
    const float a4 = fabsf(v1.x), a5 = fabsf(v1.y), a6 = fabsf(v1.z), a7 = fabsf(v1.w);
    const float b0 = fabsf(p0.x), b1 = fabsf(p0.y), b2 = fabsf(p0.z), b3 = fabsf(p0.w);
    const float b4 = fabsf(p1.x), b5 = fabsf(p1.y), b6 = fabsf(p1.z), b7 = fabsf(p1.w);

    // own 8-chunk prefix
    {
        float p = a0;
        p = fmaf(q, p, a1); p = fmaf(q, p, a2); p = fmaf(q, p, a3);
        p = fmaf(q, p, a4); p = fmaf(q, p, a5); p = fmaf(q, p, a6);
        p = fmaf(q, p, a7);
        Pe[NH8 + tid] = p;
    }

    __syncthreads();

    // ---- exact init over the 100-tap window:
    //      M[t0-1] = w0*( sum_{i=1..12} q^{8(i-1)} P8[tid-i] + q^96 * corr4 )
    //      corr4 = q^3 b0 + q^2 b1 + q b2 + b3 (elements 8t-100..8t-97 = pv0)
    float acc = fmaf(q, fmaf(q, fmaf(q, b0, b1), b2), b3);   // corr4
    #pragma unroll
    for (int j = 0; j < NH8; ++j)          // deepest chunk first (idx tid)
        acc = fmaf(acc, q8, Pe[tid + j]);
    float M = w0 * acc;                    // == M[t0-1], exact

    // ---- 8-step recursion + gain; two coalesced nt float4 stores ----
    f32x4 o;
    M = fmaf(q, M, fmaf(w0, a0, -c3 * b0));  o.x = gain_div(v0.x, M, alpha);
    M = fmaf(q, M, fmaf(w0, a1, -c3 * b1));  o.y = gain_div(v0.y, M, alpha);
    M = fmaf(q, M, fmaf(w0, a2, -c3 * b2));  o.z = gain_div(v0.z, M, alpha);
    M = fmaf(q, M, fmaf(w0, a3, -c3 * b3));  o.w = gain_div(v0.w, M, alpha);
    __builtin_nontemporal_store(o, &o4[i40]);

    M = fmaf(q, M, fmaf(w0, a4, -c3 * b4));  o.x = gain_div(v1.x, M, alpha);
    M = fmaf(q, M, fmaf(w0, a5, -c3 * b5));  o.y = gain_div(v1.y, M, alpha);
    M = fmaf(q, M, fmaf(w0, a6, -c3 * b6));  o.z = gain_div(v1.z, M, alpha);
    M = fmaf(q, M, fmaf(w0, a7, -c3 * b7));  o.w = gain_div(v1.w, M, alpha);
    __builtin_nontemporal_store(o, &o4[i40 + 1]);
}

extern "C" void kernel_launch(void* const* d_in, const int* in_sizes, int n_in,
                              void* d_out, int out_size, void* d_ws, size_t ws_size,
                              hipStream_t stream) {
    const float* x         = (const float*)d_in[0];
    const float* alpha_raw = (const float*)d_in[1];
    const float* log_s     = (const float*)d_in[2];
    float* out             = (float*)d_out;
    const int nrows = in_sizes[0] / T;   // B*KC = 4096
    agc_kernel<<<nrows * NSEG, BLOCK, 0, stream>>>(x, alpha_raw, log_s, out);
}

// Round 5
// 227.343 us; speedup vs baseline: 1.0405x; 1.0405x over previous
//
#include <hip/hip_runtime.h>
#include <math.h>

// PerBandSoftAGC: out = x / (clip(EMA_FIR(|x|), eps)^alpha + delta)
// EMA FIR (L=100 taps j=0..99, geometric) via exact sliding recursion:
//   M[t] = q*M[t-1] + w0*|x[t]| - w0*q^100 * |x[t-100]|
// R6: no LDS staging; tail-drop chunk = second coalesced global load; fp32;
//     chunk-prefix Horner init; nt store.  (best: 68us dispatch)
// R7: CHUNK=8 halved waves -> REGRESSED to 81us. Lesson: latency/parallelism
//     bound; wave count is the lever, per-thread overhead is not.
// R8: wave-independent streaming. Work unit = one wave (64 lanes x 4 elems).
//     The tail-drop load x4[i-25] of lanes 0..24 IS the 25-chunk halo, so the
//     separate halo load dies. Pe is wave-private -> __syncthreads replaced
//     by a same-wave lgkmcnt(0) fence (DS ops of a wave execute in order).
//     No block-wide vmcnt(0) drain, no 8-wave rendezvous; blocks are 4
//     independent waves. Same wave count as R6 (8.4M threads).

constexpr int T      = 8192;
constexpr int KC_    = 128;
constexpr int BLOCK  = 256;          // 4 independent waves per block
constexpr int WPB    = BLOCK / 64;   // waves per block
constexpr int CHUNK  = 4;
constexpr int WELE   = 64 * CHUNK;   // 256 elements per wave
constexpr int WPR    = T / WELE;     // 32 waves per row
constexpr int NHALO  = 25;           // 100 = 25 chunks of 4
constexpr float EPS_   = 1e-6f;
constexpr float DELTA_ = 0.1f;
constexpr float LOG2E  = 1.4426950408889634f;

typedef float f32x4 __attribute__((ext_vector_type(4)));

__device__ __forceinline__ float fast_sigmoid(float x) {
    const float e = __builtin_amdgcn_exp2f(-x * LOG2E);
    return __builtin_amdgcn_rcpf(1.0f + e);
}

__device__ __forceinline__ float gain_div(float xv, float M, float alpha) {
    const float Mc = fmaxf(M, EPS_);
    // Mc^alpha = exp2(alpha * log2(Mc)); v_log_f32 is log2, v_exp_f32 is exp2
    const float g  = __builtin_amdgcn_exp2f(alpha * __builtin_amdgcn_logf(Mc)) + DELTA_;
    return xv * __builtin_amdgcn_rcpf(g);   // g >= delta = 0.1, rcp safe
}

__global__ __launch_bounds__(BLOCK, 8) void agc_kernel(
    const float* __restrict__ x,
    const float* __restrict__ alpha_raw,
    const float* __restrict__ log_s,
    float* __restrict__ out)
{
    // wave-private prefix regions: 25 halo + 64 own (+pad) each
    __shared__ float Pe[WPB][92];

    const int tid  = threadIdx.x;
    const int lane = tid & 63;
    const int wv   = tid >> 6;
    const int gw   = blockIdx.x * WPB + wv;   // global wave id
    const int row  = gw / WPR;
    const int wrow = gw & (WPR - 1);          // wave index within row
    const int kc   = row & (KC_ - 1);
    const float* __restrict__ xrow = x + (size_t)row * T;
    float* __restrict__ orow       = out + (size_t)row * T;
    const f32x4* __restrict__ x4   = reinterpret_cast<const f32x4*>(xrow);
    f32x4* __restrict__ o4         = reinterpret_cast<f32x4*>(orow);

    const int i4 = (wrow << 6) + lane;        // own float4 index within row

    // ---- two coalesced float4 loads: own chunk + tail-drop chunk ----
    const f32x4 v = x4[i4];
    f32x4 pv = {0.0f, 0.0f, 0.0f, 0.0f};
    if (wrow != 0 || lane >= NHALO)           // zeros before row start
        pv = x4[i4 - NHALO];

    // ---- per-channel scalars (wave-uniform) ----
    const float s     = fast_sigmoid(log_s[kc]);
    const float alpha = 0.5f * fast_sigmoid(alpha_raw[kc]);
    const float q     = 1.0f - s;
    const float lq    = __builtin_amdgcn_logf(q);          // log2(q)
    const float q4    = (q * q) * (q * q);
    const float q8    = q4 * q4;
    const float q100  = __builtin_amdgcn_exp2f(100.0f * lq);
    const float norm  = (1.0f - q100) + 1e-8f;   // sum of unnormalized weights
    const float w0    = s / norm;                // normalized weight j=0
    const float c3    = w0 * q100;               // tail-drop coefficient

    const float a0 = fabsf(v.x),  a1 = fabsf(v.y),  a2 = fabsf(v.z),  a3 = fabsf(v.w);
    const float b0 = fabsf(pv.x), b1 = fabsf(pv.y), b2 = fabsf(pv.z), b3 = fabsf(pv.w);

    // ---- chunk prefixes: P = q^3|e0| + q^2|e1| + q|e2| + |e3| ----
    const float pA = fmaf(q, fmaf(q, fmaf(q, a0, a1), a2), a3);   // own chunk
    const float pB = fmaf(q, fmaf(q, fmaf(q, b0, b1), b2), b3);   // chunk lane-25

    Pe[wv][NHALO + lane] = pA;
    if (lane < NHALO) Pe[wv][lane] = pB;      // tail prefix IS the halo prefix

    // same-wave DS ordering: LDS ops of one wave execute in order; wait for
    // the writes to land, memory clobber stops compiler reordering the reads.
    asm volatile("s_waitcnt lgkmcnt(0)" ::: "memory");

    // ---- exact init over 25 chunk prefixes (100 taps exactly):
    //      M[t0-1] = w0 * sum_{j=0..24} q^{4(24-j)} * Pe[wv][lane+j]
    //      even/odd split (step q^8) -> two ~12-FMA chains, combined by q^4
    float accE = Pe[wv][lane];
    float accO = Pe[wv][lane + 1];
    #pragma unroll
    for (int j = 2; j <= 24; j += 2) accE = fmaf(accE, q8, Pe[wv][lane + j]);
    #pragma unroll
    for (int j = 3; j <= 23; j += 2) accO = fmaf(accO, q8, Pe[wv][lane + j]);
    float M = w0 * fmaf(q4, accO, accE);      // == M[t0-1], exact

    // ---- 4-step recursion + gain; one coalesced nt float4 store ----
    f32x4 o;
    M = fmaf(q, M, fmaf(w0, a0, -c3 * b0));  o.x = gain_div(v.x, M, alpha);
    M = fmaf(q, M, fmaf(w0, a1, -c3 * b1));  o.y = gain_div(v.y, M, alpha);
    M = fmaf(q, M, fmaf(w0, a2, -c3 * b2));  o.z = gain_div(v.z, M, alpha);
    M = fmaf(q, M, fmaf(w0, a3, -c3 * b3));  o.w = gain_div(v.w, M, alpha);
    __builtin_nontemporal_store(o, &o4[i4]);
}

extern "C" void kernel_launch(void* const* d_in, const int* in_sizes, int n_in,
                              void* d_out, int out_size, void* d_ws, size_t ws_size,
                              hipStream_t stream) {
    const float* x         = (const float*)d_in[0];
    const float* alpha_raw = (const float*)d_in[1];
    const float* log_s     = (const float*)d_in[2];
    float* out             = (float*)d_out;
    const int nrows = in_sizes[0] / T;            // B*KC = 4096
    const int nblocks = nrows * (T / WELE) / WPB; // 32768
    agc_kernel<<<nblocks, BLOCK, 0, stream>>>(x, alpha_raw, log_s, out);
}